// Round 8
// baseline (17482.729 us; speedup 1.0000x reference)
//
#include <hip/hip_runtime.h>
#include <cfloat>

// Problem constants
#define NROWS 16384
#define INDIM 2048
#define DIMV  1024
#define NCODE 8192

__device__ inline float clip10(float x) { return fminf(fmaxf(x, -10.f), 10.f); }

__device__ inline float block_sum256(float v, float* sm) {
#pragma unroll
  for (int off = 32; off > 0; off >>= 1) v += __shfl_down(v, off, 64);
  int lane = threadIdx.x & 63, w = threadIdx.x >> 6;
  if (lane == 0) sm[w] = v;
  __syncthreads();
  float r = 0.f;
  if (threadIdx.x == 0) r = sm[0] + sm[1] + sm[2] + sm[3];
  return r;  // valid on thread 0 only
}

__global__ void zero_kernel(float* __restrict__ p, int n) {
  int i = blockIdx.x * 256 + threadIdx.x;
  if (i < n) p[i] = 0.f;
}

// OpenBLAS level3 K-panel boundaries (GEMM_Q=384, halving rule):
//   K=2048 -> 384,384,384,384,256,256 ; K=1024 -> 384,320,320
template <int KSEL>
__device__ inline bool kfold(int kend) {
  if (KSEL == 0)
    return kend == 384 || kend == 768 || kend == 1152 || kend == 1536 || kend == 1792 ||
           kend == 2048;
  return kend == 384 || kend == 704 || kend == 1024;
}

// ============== np-faithful fp32 GEMM: C = op(A)@B + bias ==================
// Sequential-k FMA chain per element, folded at OpenBLAS K-panel boundaries.
// 64x64 tile, BK=32, 256 threads, 4x4 per thread. (round-5 proven, unchanged)
template <int KSEL, bool CLIP>
__global__ __launch_bounds__(256) void gemm_np(const float* __restrict__ A,
                                               const float* __restrict__ B,
                                               const float* __restrict__ bias,
                                               float* __restrict__ C, int M, int N, int K) {
  __shared__ float As[32][68];  // [k][m]
  __shared__ float Bs[32][68];  // [k][n]
  const int tid = threadIdx.x;
  const int tx = tid & 15, ty = tid >> 4;
  const int row0 = blockIdx.y * 64;
  const int col0 = blockIdx.x * 64;
  float cur[4][4], tot[4][4];
#pragma unroll
  for (int i = 0; i < 4; ++i)
#pragma unroll
    for (int j = 0; j < 4; ++j) { cur[i][j] = 0.f; tot[i][j] = 0.f; }

  for (int k0 = 0; k0 < K; k0 += 32) {
#pragma unroll
    for (int l = 0; l < 2; ++l) {
      int s = tid + 256 * l;
      int r = s >> 3;
      int kq = (s & 7) << 2;
      float4 v = *reinterpret_cast<const float4*>(&A[(size_t)(row0 + r) * K + k0 + kq]);
      if (CLIP) { v.x = clip10(v.x); v.y = clip10(v.y); v.z = clip10(v.z); v.w = clip10(v.w); }
      As[kq + 0][r] = v.x; As[kq + 1][r] = v.y; As[kq + 2][r] = v.z; As[kq + 3][r] = v.w;
    }
#pragma unroll
    for (int l = 0; l < 2; ++l) {
      int s = tid + 256 * l;
      int kr = s >> 4;
      int c4 = (s & 15) << 2;
      *reinterpret_cast<float4*>(&Bs[kr][c4]) =
          *reinterpret_cast<const float4*>(&B[(size_t)(k0 + kr) * N + col0 + c4]);
    }
    __syncthreads();
#pragma unroll
    for (int kk = 0; kk < 32; ++kk) {  // k strictly ascending
      float4 a = *reinterpret_cast<const float4*>(&As[kk][ty * 4]);
      float4 b = *reinterpret_cast<const float4*>(&Bs[kk][tx * 4]);
      float da[4] = {a.x, a.y, a.z, a.w};
      float db[4] = {b.x, b.y, b.z, b.w};
#pragma unroll
      for (int i = 0; i < 4; ++i)
#pragma unroll
        for (int j = 0; j < 4; ++j) cur[i][j] = fmaf(da[i], db[j], cur[i][j]);
    }
    __syncthreads();
    if (kfold<KSEL>(k0 + 32)) {
#pragma unroll
      for (int i = 0; i < 4; ++i)
#pragma unroll
        for (int j = 0; j < 4; ++j) { tot[i][j] = __fadd_rn(tot[i][j], cur[i][j]); cur[i][j] = 0.f; }
    }
  }
#pragma unroll
  for (int i = 0; i < 4; ++i) {
    int row = row0 + ty * 4 + i;
#pragma unroll
    for (int j = 0; j < 4; ++j) {
      int col = col0 + tx * 4 + j;
      C[(size_t)row * N + col] = __fadd_rn(tot[i][j], bias[col]);
    }
  }
}

// ===== numpy pairwise row-sum of squares (AVX-512 base-case emulation) ======
__global__ __launch_bounds__(256) void rowsq_np(const float* __restrict__ X, int nrows,
                                                float* __restrict__ out) {
  int row = blockIdx.x * 256 + threadIdx.x;
  if (row >= nrows) return;
  const float* rp = X + (size_t)row * 1024;
  float Bres[8];
#pragma unroll
  for (int blk = 0; blk < 8; ++blk) {
    const float* p = rp + blk * 128;
    float x[16];
#pragma unroll
    for (int L = 0; L < 16; ++L) {
      float m0 = __fmul_rn(p[L], p[L]);
      float m1 = __fmul_rn(p[64 + L], p[64 + L]);
      float r0 = __fadd_rn(m0, m1);
      float m2 = __fmul_rn(p[16 + L], p[16 + L]);
      float m3 = __fmul_rn(p[80 + L], p[80 + L]);
      float r1 = __fadd_rn(m2, m3);
      float m4 = __fmul_rn(p[32 + L], p[32 + L]);
      float m5 = __fmul_rn(p[96 + L], p[96 + L]);
      float r2 = __fadd_rn(m4, m5);
      float m6 = __fmul_rn(p[48 + L], p[48 + L]);
      float m7 = __fmul_rn(p[112 + L], p[112 + L]);
      float r3 = __fadd_rn(m6, m7);
      x[L] = __fadd_rn(__fadd_rn(r0, r1), __fadd_rn(r2, r3));
    }
    float z[4];
#pragma unroll
    for (int i = 0; i < 4; ++i)
      z[i] = __fadd_rn(__fadd_rn(x[i], x[i + 8]), __fadd_rn(x[i + 4], x[i + 12]));
    Bres[blk] = __fadd_rn(__fadd_rn(z[0], z[2]), __fadd_rn(z[1], z[3]));
  }
  float s01 = __fadd_rn(Bres[0], Bres[1]);
  float s23 = __fadd_rn(Bres[2], Bres[3]);
  float s45 = __fadd_rn(Bres[4], Bres[5]);
  float s67 = __fadd_rn(Bres[6], Bres[7]);
  out[row] = __fadd_rn(__fadd_rn(s01, s23), __fadd_rn(s45, s67));
}

// ========== np-faithful distance + per-tile argmin, v4 (no-spill) ==========
// Bit-identical chains to round 7 (k strictly ascending, folds {384,704,1024};
// d = fl(fl(z2 - 2G) + c2); first-index tie-break at every level).
// 128 rows x 128 codes, 512 threads, per-thread 8 rows x 4 codes ->
// cur[8][4]+tot[8][4] = 64 accumulator VGPRs (round 7's 8x8 = 128 spilled to
// scratch: 1.4 GB WRITE_SIZE). XOR k-quad swizzle on BOTH Zs and Cs:
//   addr(r,kq) = r*20 + (kq ^ (((r>>3)&3)<<2))  -- bijective within the row
// Cs read quartet cx,cx+8,cx+16,cx+24 (same 20*cx mod 32 base) gets 4 distinct
// XOR perms -> 4 distinct banks -> conflict-free b128 reads.
__device__ inline int zaddr(int r, int kq) {
  return r * 20 + (kq ^ ((((r) >> 3) & 3) << 2));
}
__global__ __launch_bounds__(512, 4) void dist_np3(const float* __restrict__ Z,
                                                   const float* __restrict__ CB,
                                                   const float* __restrict__ z2,
                                                   const float* __restrict__ c2,
                                                   float* __restrict__ pv,
                                                   int* __restrict__ pi) {
  __shared__ float Zs[128 * 20];
  __shared__ float Cs[128 * 20];
  __shared__ float redv[128][33];
  __shared__ int redi[128][33];
  const int tid = threadIdx.x;
  const int cx = tid & 31, ry = tid >> 5;  // cx: code group; ry in [0,16): row octet
  const int row0 = blockIdx.y * 128;
  const int col0 = blockIdx.x * 128;
  float cur[8][4], tot[8][4];
#pragma unroll
  for (int m = 0; m < 8; ++m)
#pragma unroll
    for (int n = 0; n < 4; ++n) { cur[m][n] = 0.f; tot[m][n] = 0.f; }

  for (int k0 = 0; k0 < DIMV; k0 += 16) {
    {  // stage: 128 rows x 16 k for both Z and CB; 1 float4 each per thread
      int r = tid >> 2;          // 0..127
      int kq = (tid & 3) << 2;   // 0,4,8,12
      float4 vz = *reinterpret_cast<const float4*>(&Z[(size_t)(row0 + r) * DIMV + k0 + kq]);
      *reinterpret_cast<float4*>(&Zs[zaddr(r, kq)]) = vz;
      float4 vc = *reinterpret_cast<const float4*>(&CB[(size_t)(col0 + r) * DIMV + k0 + kq]);
      *reinterpret_cast<float4*>(&Cs[zaddr(r, kq)]) = vc;
    }
    __syncthreads();
#pragma unroll
    for (int kq = 0; kq < 16; kq += 4) {  // k quads ascending
      float4 cb[4];
#pragma unroll
      for (int n = 0; n < 4; ++n)
        cb[n] = *reinterpret_cast<const float4*>(&Cs[zaddr(cx + 32 * n, kq)]);
#pragma unroll
      for (int m = 0; m < 8; ++m) {
        float4 za = *reinterpret_cast<const float4*>(&Zs[zaddr(ry * 8 + m, kq)]);
#pragma unroll
        for (int n = 0; n < 4; ++n) {  // per output: x,y,z,w = k ascending
          cur[m][n] = fmaf(za.x, cb[n].x, cur[m][n]);
          cur[m][n] = fmaf(za.y, cb[n].y, cur[m][n]);
          cur[m][n] = fmaf(za.z, cb[n].z, cur[m][n]);
          cur[m][n] = fmaf(za.w, cb[n].w, cur[m][n]);
        }
      }
    }
    __syncthreads();
    if (kfold<1>(k0 + 16)) {
#pragma unroll
      for (int m = 0; m < 8; ++m)
#pragma unroll
        for (int n = 0; n < 4; ++n) { tot[m][n] = __fadd_rn(tot[m][n], cur[m][n]); cur[m][n] = 0.f; }
    }
  }

  float c2v[4];
#pragma unroll
  for (int n = 0; n < 4; ++n) c2v[n] = c2[col0 + cx + 32 * n];

#pragma unroll
  for (int m = 0; m < 8; ++m) {
    int row = ry * 8 + m;
    float z2v = z2[row0 + row];
    float best = FLT_MAX;
    int bi = 0x7fffffff;
#pragma unroll
    for (int n = 0; n < 4; ++n) {  // n ascending = code ascending within thread
      float g2 = __fmul_rn(2.0f, tot[m][n]);  // exact (x2)
      float t = __fsub_rn(z2v, g2);           // fl(z2 - 2G)
      float d = __fadd_rn(t, c2v[n]);         // fl(... + c2)
      int code = col0 + cx + 32 * n;
      if (d < best || (d == best && code < bi)) { best = d; bi = code; }
    }
    redv[row][cx] = best;
    redi[row][cx] = bi;
  }
  __syncthreads();
  if (tid < 128) {  // per-row reduce over 32 code groups, index tiebreak
    float best = redv[tid][0];
    int bi = redi[tid][0];
#pragma unroll
    for (int t = 1; t < 32; ++t) {
      float v = redv[tid][t];
      int io = redi[tid][t];
      if (v < best || (v == best && io < bi)) { best = v; bi = io; }
    }
    pv[(size_t)(row0 + tid) * 64 + blockIdx.x] = best;
    pi[(size_t)(row0 + tid) * 64 + blockIdx.x] = bi;
  }
}

// -------- final argmin across 64 code tiles + usage histogram ---------------
__global__ __launch_bounds__(256) void argmin_final(const float* __restrict__ pv,
                                                    const int* __restrict__ pi,
                                                    float* __restrict__ out_ids,
                                                    int* __restrict__ ids,
                                                    float* __restrict__ usage) {
  int row = blockIdx.x * 256 + threadIdx.x;
  const float* pr = pv + (size_t)row * 64;
  const int* pir = pi + (size_t)row * 64;
  float best = pr[0];
  int bi = pir[0];
  for (int t = 1; t < 64; ++t) {  // ascending tiles = ascending code ranges
    float v = pr[t];
    if (v < best) { best = v; bi = pir[t]; }
  }
  ids[row] = bi;
  out_ids[row] = (float)bi;
  atomicAdd(&usage[bi], 1.0f);  // exact integer-valued floats: order-independent
}

// ---------------- z_q = codebook[ids] (float32 out) ----------------
__global__ __launch_bounds__(256) void gather_kernel(const int* __restrict__ ids,
                                                     const float* __restrict__ CB,
                                                     float* __restrict__ zq) {
  int row = blockIdx.x;
  int id = ids[row];
  *reinterpret_cast<float4*>(&zq[(size_t)row * DIMV + threadIdx.x * 4]) =
      *reinterpret_cast<const float4*>(&CB[(size_t)id * DIMV + threadIdx.x * 4]);
}

// -------- decoder GEMM 1: h = CB[ids] @ Wd + bd (plain fp32) ---------
__global__ __launch_bounds__(256) void gemm_dec1(const int* __restrict__ ids,
                                                 const float* __restrict__ CB,
                                                 const float* __restrict__ B,
                                                 const float* __restrict__ bias,
                                                 float* __restrict__ C) {
  __shared__ float As[32][68];
  __shared__ float Bs[32][68];
  __shared__ int sid[64];
  const int tid = threadIdx.x;
  const int tx = tid & 15, ty = tid >> 4;
  const int row0 = blockIdx.y * 64;
  const int col0 = blockIdx.x * 64;
  if (tid < 64) sid[tid] = ids[row0 + tid];
  __syncthreads();
  float acc[4][4];
#pragma unroll
  for (int i = 0; i < 4; ++i)
#pragma unroll
    for (int j = 0; j < 4; ++j) acc[i][j] = 0.f;

  for (int k0 = 0; k0 < DIMV; k0 += 32) {
#pragma unroll
    for (int l = 0; l < 2; ++l) {
      int s = tid + 256 * l;
      int r = s >> 3;
      int kq = (s & 7) << 2;
      float4 v = *reinterpret_cast<const float4*>(&CB[(size_t)sid[r] * DIMV + k0 + kq]);
      As[kq + 0][r] = v.x; As[kq + 1][r] = v.y; As[kq + 2][r] = v.z; As[kq + 3][r] = v.w;
    }
#pragma unroll
    for (int l = 0; l < 2; ++l) {
      int s = tid + 256 * l;
      int kr = s >> 4;
      int c4 = (s & 15) << 2;
      *reinterpret_cast<float4*>(&Bs[kr][c4]) =
          *reinterpret_cast<const float4*>(&B[(size_t)(k0 + kr) * DIMV + col0 + c4]);
    }
    __syncthreads();
#pragma unroll
    for (int kk = 0; kk < 32; ++kk) {
      float4 a = *reinterpret_cast<const float4*>(&As[kk][ty * 4]);
      float4 b = *reinterpret_cast<const float4*>(&Bs[kk][tx * 4]);
      float da[4] = {a.x, a.y, a.z, a.w};
      float db[4] = {b.x, b.y, b.z, b.w};
#pragma unroll
      for (int i = 0; i < 4; ++i)
#pragma unroll
        for (int j = 0; j < 4; ++j) acc[i][j] = fmaf(da[i], db[j], acc[i][j]);
    }
    __syncthreads();
  }
#pragma unroll
  for (int i = 0; i < 4; ++i) {
    int row = row0 + ty * 4 + i;
#pragma unroll
    for (int j = 0; j < 4; ++j) {
      int col = col0 + tx * 4 + j;
      C[(size_t)row * DIMV + col] = acc[i][j] + bias[col];
    }
  }
}

// -- decoder GEMM 2: recon = h @ Wo + bo (f32 out) + fused recon-loss partial --
__global__ __launch_bounds__(256) void gemm_dec2(const float* __restrict__ A,
                                                 const float* __restrict__ B,
                                                 const float* __restrict__ bias,
                                                 const float* __restrict__ roi,
                                                 float* __restrict__ Cout,
                                                 float* __restrict__ part) {
  __shared__ float As[32][68];
  __shared__ float Bs[32][68];
  __shared__ float sm[4];
  const int tid = threadIdx.x;
  const int tx = tid & 15, ty = tid >> 4;
  const int row0 = blockIdx.y * 64;
  const int col0 = blockIdx.x * 64;
  float acc[4][4];
#pragma unroll
  for (int i = 0; i < 4; ++i)
#pragma unroll
    for (int j = 0; j < 4; ++j) acc[i][j] = 0.f;

  for (int k0 = 0; k0 < DIMV; k0 += 32) {
#pragma unroll
    for (int l = 0; l < 2; ++l) {
      int s = tid + 256 * l;
      int r = s >> 3;
      int kq = (s & 7) << 2;
      float4 v = *reinterpret_cast<const float4*>(&A[(size_t)(row0 + r) * DIMV + k0 + kq]);
      As[kq + 0][r] = v.x; As[kq + 1][r] = v.y; As[kq + 2][r] = v.z; As[kq + 3][r] = v.w;
    }
#pragma unroll
    for (int l = 0; l < 2; ++l) {
      int s = tid + 256 * l;
      int kr = s >> 4;
      int c4 = (s & 15) << 2;
      *reinterpret_cast<float4*>(&Bs[kr][c4]) =
          *reinterpret_cast<const float4*>(&B[(size_t)(k0 + kr) * INDIM + col0 + c4]);
    }
    __syncthreads();
#pragma unroll
    for (int kk = 0; kk < 32; ++kk) {
      float4 a = *reinterpret_cast<const float4*>(&As[kk][ty * 4]);
      float4 b = *reinterpret_cast<const float4*>(&Bs[kk][tx * 4]);
      float da[4] = {a.x, a.y, a.z, a.w};
      float db[4] = {b.x, b.y, b.z, b.w};
#pragma unroll
      for (int i = 0; i < 4; ++i)
#pragma unroll
        for (int j = 0; j < 4; ++j) acc[i][j] = fmaf(da[i], db[j], acc[i][j]);
    }
    __syncthreads();
  }

  float s = 0.f;
#pragma unroll
  for (int i = 0; i < 4; ++i) {
    int row = row0 + ty * 4 + i;
    int col = col0 + tx * 4;
    float4 x = *reinterpret_cast<const float4*>(&roi[(size_t)row * INDIM + col]);
    float xs[4] = {x.x, x.y, x.z, x.w};
    float vals[4];
#pragma unroll
    for (int j = 0; j < 4; ++j) {
      float val = acc[i][j] + bias[col + j];
      float d = val - clip10(xs[j]);
      s += d * d;
      vals[j] = val;
    }
    *reinterpret_cast<float4*>(&Cout[(size_t)row * INDIM + col]) =
        make_float4(vals[0], vals[1], vals[2], vals[3]);
  }
  float t = block_sum256(s, sm);
  if (tid == 0) part[blockIdx.y * gridDim.x + blockIdx.x] = t;
}

// ---------------- embedding loss partial: sum((CB[id]-ze)^2) per row ---------
__global__ __launch_bounds__(256) void emb_partial(const int* __restrict__ ids,
                                                   const float* __restrict__ CB,
                                                   const float* __restrict__ ze,
                                                   float* __restrict__ part) {
  __shared__ float sm[4];
  int row = blockIdx.x;
  int id = ids[row];
  float4 q = *reinterpret_cast<const float4*>(&CB[(size_t)id * DIMV + threadIdx.x * 4]);
  float4 z = *reinterpret_cast<const float4*>(&ze[(size_t)row * DIMV + threadIdx.x * 4]);
  float dx = q.x - z.x, dy = q.y - z.y, dz = q.z - z.z, dw = q.w - z.w;
  float t = block_sum256(dx * dx + dy * dy + dz * dz + dw * dw, sm);
  if (threadIdx.x == 0) part[row] = t;
}

// ---------------- final reduce: 4 scalar losses ------------------------------
__global__ __launch_bounds__(256) void loss_final(const float* __restrict__ part1,
                                                  const float* __restrict__ part2,
                                                  float* __restrict__ scal) {
  __shared__ float sm[4];
  float s1 = 0.f;
  for (int i = threadIdx.x; i < 8192; i += 256) s1 += part1[i];
  float s2 = 0.f;
  for (int i = threadIdx.x; i < NROWS; i += 256) s2 += part2[i];
  float t1 = block_sum256(s1, sm);
  __syncthreads();
  float t2 = block_sum256(s2, sm);
  if (threadIdx.x == 0) {
    float recon_loss = t1 / 33554432.f;  // N * INDIM
    float emb = t2 / 16777216.f;         // N * DIM
    scal[0] = recon_loss + emb + 0.25f * emb;  // vq = recon + embed + 0.25*commit
    scal[1] = recon_loss;
    scal[2] = emb;
    scal[3] = emb;  // commitment forward value == embedding
  }
}

extern "C" void kernel_launch(void* const* d_in, const int* in_sizes, int n_in,
                              void* d_out, int out_size, void* d_ws, size_t ws_size,
                              hipStream_t stream) {
  const float* roi = (const float*)d_in[0];
  const float* Wp = (const float*)d_in[1];
  const float* bp = (const float*)d_in[2];
  const float* We = (const float*)d_in[3];
  const float* be = (const float*)d_in[4];
  const float* CB = (const float*)d_in[5];
  const float* Wd = (const float*)d_in[6];
  const float* bd = (const float*)d_in[7];
  const float* Wo = (const float*)d_in[8];
  const float* bo = (const float*)d_in[9];

  // float32 output layout: ids[N], z_q[N*DIM], recon[N*INDIM], 4 scalars, usage
  float* out = (float*)d_out;
  float* out_ids = out;
  float* out_zq = out + NROWS;
  float* out_recon = out_zq + (size_t)NROWS * DIMV;
  float* out_scal = out_recon + (size_t)NROWS * INDIM;
  float* out_usage = out_scal + 4;

  // workspace (~145 MB)
  float* ws = (float*)d_ws;
  float* z1 = ws;                                   // N*DIM (reused as h)
  float* ze = z1 + (size_t)NROWS * DIMV;            // N*DIM
  float* z2 = ze + (size_t)NROWS * DIMV;            // N
  float* c2 = z2 + NROWS;                           // NCODE
  float* pv = c2 + NCODE;                           // N*64
  int* pi = (int*)(pv + (size_t)NROWS * 64);        // N*64
  int* ids = pi + (size_t)NROWS * 64;               // N
  float* part1 = (float*)(ids + NROWS);             // 8192 (recon partials)
  float* part2 = part1 + 8192;                      // N (emb partials)

  zero_kernel<<<32, 256, 0, stream>>>(out_usage, NCODE);  // idempotent per call

  // z1 = clip(roi) @ Wp + bp ; z_e = z1 @ We + be  (np/OpenBLAS-faithful fp32)
  gemm_np<0, true><<<dim3(DIMV / 64, NROWS / 64), 256, 0, stream>>>(roi, Wp, bp, z1, NROWS,
                                                                    DIMV, INDIM);
  gemm_np<1, false><<<dim3(DIMV / 64, NROWS / 64), 256, 0, stream>>>(z1, We, be, ze, NROWS,
                                                                     DIMV, DIMV);
  // z2 = np.sum(z_e*z_e,1), c2 = np.sum(CB*CB,1)  (numpy pairwise emulation)
  rowsq_np<<<NROWS / 256, 256, 0, stream>>>(ze, NROWS, z2);
  rowsq_np<<<NCODE / 256, 256, 0, stream>>>(CB, NCODE, c2);

  // d = fl(fl(z2 - 2*(z_e@CB^T)) + c2); argmin with np first-index ties
  dist_np3<<<dim3(NCODE / 128, NROWS / 128), 512, 0, stream>>>(ze, CB, z2, c2, pv, pi);
  argmin_final<<<NROWS / 256, 256, 0, stream>>>(pv, pi, out_ids, ids, out_usage);
  gather_kernel<<<NROWS, 256, 0, stream>>>(ids, CB, out_zq);

  // decoder: h = CB[ids] @ Wd + bd ; recon = h @ Wo + bo (+ fused recon-loss)
  gemm_dec1<<<dim3(DIMV / 64, NROWS / 64), 256, 0, stream>>>(ids, CB, Wd, bd, z1);
  gemm_dec2<<<dim3(INDIM / 64, NROWS / 64), 256, 0, stream>>>(z1, Wo, bo, roi, out_recon,
                                                              part1);
  // embedding loss partials + final scalars
  emb_partial<<<NROWS, 256, 0, stream>>>(ids, CB, ze, part2);
  loss_final<<<1, 256, 0, stream>>>(part1, part2, out_scal);
}

// Round 9
// 6862.749 us; speedup vs baseline: 2.5475x; 2.5475x over previous
//
#include <hip/hip_runtime.h>
#include <cfloat>

// Problem constants
#define NROWS 16384
#define INDIM 2048
#define DIMV  1024
#define NCODE 8192

__device__ inline float clip10(float x) { return fminf(fmaxf(x, -10.f), 10.f); }

__device__ inline float block_sum256(float v, float* sm) {
#pragma unroll
  for (int off = 32; off > 0; off >>= 1) v += __shfl_down(v, off, 64);
  int lane = threadIdx.x & 63, w = threadIdx.x >> 6;
  if (lane == 0) sm[w] = v;
  __syncthreads();
  float r = 0.f;
  if (threadIdx.x == 0) r = sm[0] + sm[1] + sm[2] + sm[3];
  return r;  // valid on thread 0 only
}

__global__ void zero_kernel(float* __restrict__ p, int n) {
  int i = blockIdx.x * 256 + threadIdx.x;
  if (i < n) p[i] = 0.f;
}

// OpenBLAS level3 K-panel boundaries (GEMM_Q=384, halving rule):
//   K=2048 -> 384,384,384,384,256,256 ; K=1024 -> 384,320,320
template <int KSEL>
__device__ inline bool kfold(int kend) {
  if (KSEL == 0)
    return kend == 384 || kend == 768 || kend == 1152 || kend == 1536 || kend == 1792 ||
           kend == 2048;
  return kend == 384 || kend == 704 || kend == 1024;
}

// ============== np-faithful fp32 GEMM: C = op(A)@B + bias ==================
// Sequential-k FMA chain per element, folded at OpenBLAS K-panel boundaries.
// 64x64 tile, BK=32, 256 threads, 4x4 per thread. (round-5 proven, unchanged)
template <int KSEL, bool CLIP>
__global__ __launch_bounds__(256) void gemm_np(const float* __restrict__ A,
                                               const float* __restrict__ B,
                                               const float* __restrict__ bias,
                                               float* __restrict__ C, int M, int N, int K) {
  __shared__ float As[32][68];  // [k][m]
  __shared__ float Bs[32][68];  // [k][n]
  const int tid = threadIdx.x;
  const int tx = tid & 15, ty = tid >> 4;
  const int row0 = blockIdx.y * 64;
  const int col0 = blockIdx.x * 64;
  float cur[4][4], tot[4][4];
#pragma unroll
  for (int i = 0; i < 4; ++i)
#pragma unroll
    for (int j = 0; j < 4; ++j) { cur[i][j] = 0.f; tot[i][j] = 0.f; }

  for (int k0 = 0; k0 < K; k0 += 32) {
#pragma unroll
    for (int l = 0; l < 2; ++l) {
      int s = tid + 256 * l;
      int r = s >> 3;
      int kq = (s & 7) << 2;
      float4 v = *reinterpret_cast<const float4*>(&A[(size_t)(row0 + r) * K + k0 + kq]);
      if (CLIP) { v.x = clip10(v.x); v.y = clip10(v.y); v.z = clip10(v.z); v.w = clip10(v.w); }
      As[kq + 0][r] = v.x; As[kq + 1][r] = v.y; As[kq + 2][r] = v.z; As[kq + 3][r] = v.w;
    }
#pragma unroll
    for (int l = 0; l < 2; ++l) {
      int s = tid + 256 * l;
      int kr = s >> 4;
      int c4 = (s & 15) << 2;
      *reinterpret_cast<float4*>(&Bs[kr][c4]) =
          *reinterpret_cast<const float4*>(&B[(size_t)(k0 + kr) * N + col0 + c4]);
    }
    __syncthreads();
#pragma unroll
    for (int kk = 0; kk < 32; ++kk) {  // k strictly ascending
      float4 a = *reinterpret_cast<const float4*>(&As[kk][ty * 4]);
      float4 b = *reinterpret_cast<const float4*>(&Bs[kk][tx * 4]);
      float da[4] = {a.x, a.y, a.z, a.w};
      float db[4] = {b.x, b.y, b.z, b.w};
#pragma unroll
      for (int i = 0; i < 4; ++i)
#pragma unroll
        for (int j = 0; j < 4; ++j) cur[i][j] = fmaf(da[i], db[j], cur[i][j]);
    }
    __syncthreads();
    if (kfold<KSEL>(k0 + 32)) {
#pragma unroll
      for (int i = 0; i < 4; ++i)
#pragma unroll
        for (int j = 0; j < 4; ++j) { tot[i][j] = __fadd_rn(tot[i][j], cur[i][j]); cur[i][j] = 0.f; }
    }
  }
#pragma unroll
  for (int i = 0; i < 4; ++i) {
    int row = row0 + ty * 4 + i;
#pragma unroll
    for (int j = 0; j < 4; ++j) {
      int col = col0 + tx * 4 + j;
      C[(size_t)row * N + col] = __fadd_rn(tot[i][j], bias[col]);
    }
  }
}

// ===== numpy pairwise row-sum of squares (AVX-512 base-case emulation) ======
__global__ __launch_bounds__(256) void rowsq_np(const float* __restrict__ X, int nrows,
                                                float* __restrict__ out) {
  int row = blockIdx.x * 256 + threadIdx.x;
  if (row >= nrows) return;
  const float* rp = X + (size_t)row * 1024;
  float Bres[8];
#pragma unroll
  for (int blk = 0; blk < 8; ++blk) {
    const float* p = rp + blk * 128;
    float x[16];
#pragma unroll
    for (int L = 0; L < 16; ++L) {
      float m0 = __fmul_rn(p[L], p[L]);
      float m1 = __fmul_rn(p[64 + L], p[64 + L]);
      float r0 = __fadd_rn(m0, m1);
      float m2 = __fmul_rn(p[16 + L], p[16 + L]);
      float m3 = __fmul_rn(p[80 + L], p[80 + L]);
      float r1 = __fadd_rn(m2, m3);
      float m4 = __fmul_rn(p[32 + L], p[32 + L]);
      float m5 = __fmul_rn(p[96 + L], p[96 + L]);
      float r2 = __fadd_rn(m4, m5);
      float m6 = __fmul_rn(p[48 + L], p[48 + L]);
      float m7 = __fmul_rn(p[112 + L], p[112 + L]);
      float r3 = __fadd_rn(m6, m7);
      x[L] = __fadd_rn(__fadd_rn(r0, r1), __fadd_rn(r2, r3));
    }
    float z[4];
#pragma unroll
    for (int i = 0; i < 4; ++i)
      z[i] = __fadd_rn(__fadd_rn(x[i], x[i + 8]), __fadd_rn(x[i + 4], x[i + 12]));
    Bres[blk] = __fadd_rn(__fadd_rn(z[0], z[2]), __fadd_rn(z[1], z[3]));
  }
  float s01 = __fadd_rn(Bres[0], Bres[1]);
  float s23 = __fadd_rn(Bres[2], Bres[3]);
  float s45 = __fadd_rn(Bres[4], Bres[5]);
  float s67 = __fadd_rn(Bres[6], Bres[7]);
  out[row] = __fadd_rn(__fadd_rn(s01, s23), __fadd_rn(s45, s67));
}

// ========== np-faithful distance + per-tile argmin, v5 (no-spill budget) =====
// Bit-identical chains (k strictly ascending, folds {384,704,1024};
// d = fl(fl(z2 - 2G) + c2); first-index tie-break at every level).
// Tile: 128 rows x 64 codes, 256 threads, per-thread 8 rows x 4 codes.
// Register budget: cur+tot = 64 acc + cb 16 + za 4 + ~25 addr ~= 110 VGPR
// < 128 cap of launch_bounds(256,2) -> NO scratch spill (round 8's 68 GB
// HBM traffic was cur/tot spilling under a forced 64-VGPR cap).
// XOR k-quad swizzle on both Zs/Cs: addr(r,kq) = r*20 + (kq ^ (((r>>3)&3)<<2));
// za: 4 distinct bank-quads broadcast (conflict-free); cb: 2-way alias (free).
__device__ inline int zaddr(int r, int kq) {
  return r * 20 + (kq ^ ((((r) >> 3) & 3) << 2));
}
__global__ __launch_bounds__(256, 2) void dist_np4(const float* __restrict__ Z,
                                                   const float* __restrict__ CB,
                                                   const float* __restrict__ z2,
                                                   const float* __restrict__ c2,
                                                   float* __restrict__ pv,
                                                   int* __restrict__ pi) {
  __shared__ float Zs[128 * 20];
  __shared__ float Cs[64 * 20];
  __shared__ float redv[128][17];
  __shared__ int redi[128][17];
  const int tid = threadIdx.x;
  const int tx = tid & 15, ty = tid >> 4;  // tx: code group; ty in [0,16): row octet
  const int row0 = blockIdx.y * 128;
  const int col0 = blockIdx.x * 64;
  float cur[8][4], tot[8][4];
#pragma unroll
  for (int m = 0; m < 8; ++m)
#pragma unroll
    for (int n = 0; n < 4; ++n) { cur[m][n] = 0.f; tot[m][n] = 0.f; }

  for (int k0 = 0; k0 < DIMV; k0 += 16) {
    {  // stage Z: 128 rows x 16 k = 512 quads (2/thread)
#pragma unroll
      for (int l = 0; l < 2; ++l) {
        int s = tid + 256 * l;
        int r = s >> 2;
        int kq = (s & 3) << 2;
        float4 vz = *reinterpret_cast<const float4*>(&Z[(size_t)(row0 + r) * DIMV + k0 + kq]);
        *reinterpret_cast<float4*>(&Zs[zaddr(r, kq)]) = vz;
      }
      // stage CB: 64 codes x 16 k = 256 quads (1/thread)
      int rc = tid >> 2;
      int kq = (tid & 3) << 2;
      float4 vc = *reinterpret_cast<const float4*>(&CB[(size_t)(col0 + rc) * DIMV + k0 + kq]);
      *reinterpret_cast<float4*>(&Cs[zaddr(rc, kq)]) = vc;
    }
    __syncthreads();
#pragma unroll
    for (int kq = 0; kq < 16; kq += 4) {  // k quads ascending
      float4 cb[4];
#pragma unroll
      for (int n = 0; n < 4; ++n)
        cb[n] = *reinterpret_cast<const float4*>(&Cs[zaddr(tx + 16 * n, kq)]);
#pragma unroll
      for (int m = 0; m < 8; ++m) {
        float4 za = *reinterpret_cast<const float4*>(&Zs[zaddr(ty * 8 + m, kq)]);
#pragma unroll
        for (int n = 0; n < 4; ++n) {  // per output: x,y,z,w = k ascending
          cur[m][n] = fmaf(za.x, cb[n].x, cur[m][n]);
          cur[m][n] = fmaf(za.y, cb[n].y, cur[m][n]);
          cur[m][n] = fmaf(za.z, cb[n].z, cur[m][n]);
          cur[m][n] = fmaf(za.w, cb[n].w, cur[m][n]);
        }
      }
    }
    __syncthreads();
    if (kfold<1>(k0 + 16)) {
#pragma unroll
      for (int m = 0; m < 8; ++m)
#pragma unroll
        for (int n = 0; n < 4; ++n) { tot[m][n] = __fadd_rn(tot[m][n], cur[m][n]); cur[m][n] = 0.f; }
    }
  }

  float c2v[4];
#pragma unroll
  for (int n = 0; n < 4; ++n) c2v[n] = c2[col0 + tx + 16 * n];

#pragma unroll
  for (int m = 0; m < 8; ++m) {
    int row = ty * 8 + m;
    float z2v = z2[row0 + row];
    float best = FLT_MAX;
    int bi = 0x7fffffff;
#pragma unroll
    for (int n = 0; n < 4; ++n) {  // n ascending = code ascending within thread
      float g2 = __fmul_rn(2.0f, tot[m][n]);  // exact (x2)
      float t = __fsub_rn(z2v, g2);           // fl(z2 - 2G)
      float d = __fadd_rn(t, c2v[n]);         // fl(... + c2)
      int code = col0 + tx + 16 * n;
      if (d < best || (d == best && code < bi)) { best = d; bi = code; }
    }
    redv[row][tx] = best;
    redi[row][tx] = bi;
  }
  __syncthreads();
  if (tid < 128) {  // per-row reduce over 16 code groups, index tiebreak
    float best = redv[tid][0];
    int bi = redi[tid][0];
#pragma unroll
    for (int t = 1; t < 16; ++t) {
      float v = redv[tid][t];
      int io = redi[tid][t];
      if (v < best || (v == best && io < bi)) { best = v; bi = io; }
    }
    pv[(size_t)(row0 + tid) * 128 + blockIdx.x] = best;
    pi[(size_t)(row0 + tid) * 128 + blockIdx.x] = bi;
  }
}

// -------- final argmin across 128 code tiles + usage histogram --------------
__global__ __launch_bounds__(256) void argmin_final(const float* __restrict__ pv,
                                                    const int* __restrict__ pi,
                                                    float* __restrict__ out_ids,
                                                    int* __restrict__ ids,
                                                    float* __restrict__ usage) {
  int row = blockIdx.x * 256 + threadIdx.x;
  const float* pr = pv + (size_t)row * 128;
  const int* pir = pi + (size_t)row * 128;
  float best = pr[0];
  int bi = pir[0];
  for (int t = 1; t < 128; ++t) {  // ascending tiles = ascending code ranges
    float v = pr[t];
    if (v < best) { best = v; bi = pir[t]; }
  }
  ids[row] = bi;
  out_ids[row] = (float)bi;
  atomicAdd(&usage[bi], 1.0f);  // exact integer-valued floats: order-independent
}

// ---------------- z_q = codebook[ids] (float32 out) ----------------
__global__ __launch_bounds__(256) void gather_kernel(const int* __restrict__ ids,
                                                     const float* __restrict__ CB,
                                                     float* __restrict__ zq) {
  int row = blockIdx.x;
  int id = ids[row];
  *reinterpret_cast<float4*>(&zq[(size_t)row * DIMV + threadIdx.x * 4]) =
      *reinterpret_cast<const float4*>(&CB[(size_t)id * DIMV + threadIdx.x * 4]);
}

// -------- decoder GEMM 1: h = CB[ids] @ Wd + bd (plain fp32) ---------
__global__ __launch_bounds__(256) void gemm_dec1(const int* __restrict__ ids,
                                                 const float* __restrict__ CB,
                                                 const float* __restrict__ B,
                                                 const float* __restrict__ bias,
                                                 float* __restrict__ C) {
  __shared__ float As[32][68];
  __shared__ float Bs[32][68];
  __shared__ int sid[64];
  const int tid = threadIdx.x;
  const int tx = tid & 15, ty = tid >> 4;
  const int row0 = blockIdx.y * 64;
  const int col0 = blockIdx.x * 64;
  if (tid < 64) sid[tid] = ids[row0 + tid];
  __syncthreads();
  float acc[4][4];
#pragma unroll
  for (int i = 0; i < 4; ++i)
#pragma unroll
    for (int j = 0; j < 4; ++j) acc[i][j] = 0.f;

  for (int k0 = 0; k0 < DIMV; k0 += 32) {
#pragma unroll
    for (int l = 0; l < 2; ++l) {
      int s = tid + 256 * l;
      int r = s >> 3;
      int kq = (s & 7) << 2;
      float4 v = *reinterpret_cast<const float4*>(&CB[(size_t)sid[r] * DIMV + k0 + kq]);
      As[kq + 0][r] = v.x; As[kq + 1][r] = v.y; As[kq + 2][r] = v.z; As[kq + 3][r] = v.w;
    }
#pragma unroll
    for (int l = 0; l < 2; ++l) {
      int s = tid + 256 * l;
      int kr = s >> 4;
      int c4 = (s & 15) << 2;
      *reinterpret_cast<float4*>(&Bs[kr][c4]) =
          *reinterpret_cast<const float4*>(&B[(size_t)(k0 + kr) * DIMV + col0 + c4]);
    }
    __syncthreads();
#pragma unroll
    for (int kk = 0; kk < 32; ++kk) {
      float4 a = *reinterpret_cast<const float4*>(&As[kk][ty * 4]);
      float4 b = *reinterpret_cast<const float4*>(&Bs[kk][tx * 4]);
      float da[4] = {a.x, a.y, a.z, a.w};
      float db[4] = {b.x, b.y, b.z, b.w};
#pragma unroll
      for (int i = 0; i < 4; ++i)
#pragma unroll
        for (int j = 0; j < 4; ++j) acc[i][j] = fmaf(da[i], db[j], acc[i][j]);
    }
    __syncthreads();
  }
#pragma unroll
  for (int i = 0; i < 4; ++i) {
    int row = row0 + ty * 4 + i;
#pragma unroll
    for (int j = 0; j < 4; ++j) {
      int col = col0 + tx * 4 + j;
      C[(size_t)row * DIMV + col] = acc[i][j] + bias[col];
    }
  }
}

// -- decoder GEMM 2: recon = h @ Wo + bo (f32 out) + fused recon-loss partial --
__global__ __launch_bounds__(256) void gemm_dec2(const float* __restrict__ A,
                                                 const float* __restrict__ B,
                                                 const float* __restrict__ bias,
                                                 const float* __restrict__ roi,
                                                 float* __restrict__ Cout,
                                                 float* __restrict__ part) {
  __shared__ float As[32][68];
  __shared__ float Bs[32][68];
  __shared__ float sm[4];
  const int tid = threadIdx.x;
  const int tx = tid & 15, ty = tid >> 4;
  const int row0 = blockIdx.y * 64;
  const int col0 = blockIdx.x * 64;
  float acc[4][4];
#pragma unroll
  for (int i = 0; i < 4; ++i)
#pragma unroll
    for (int j = 0; j < 4; ++j) acc[i][j] = 0.f;

  for (int k0 = 0; k0 < DIMV; k0 += 32) {
#pragma unroll
    for (int l = 0; l < 2; ++l) {
      int s = tid + 256 * l;
      int r = s >> 3;
      int kq = (s & 7) << 2;
      float4 v = *reinterpret_cast<const float4*>(&A[(size_t)(row0 + r) * DIMV + k0 + kq]);
      As[kq + 0][r] = v.x; As[kq + 1][r] = v.y; As[kq + 2][r] = v.z; As[kq + 3][r] = v.w;
    }
#pragma unroll
    for (int l = 0; l < 2; ++l) {
      int s = tid + 256 * l;
      int kr = s >> 4;
      int c4 = (s & 15) << 2;
      *reinterpret_cast<float4*>(&Bs[kr][c4]) =
          *reinterpret_cast<const float4*>(&B[(size_t)(k0 + kr) * INDIM + col0 + c4]);
    }
    __syncthreads();
#pragma unroll
    for (int kk = 0; kk < 32; ++kk) {
      float4 a = *reinterpret_cast<const float4*>(&As[kk][ty * 4]);
      float4 b = *reinterpret_cast<const float4*>(&Bs[kk][tx * 4]);
      float da[4] = {a.x, a.y, a.z, a.w};
      float db[4] = {b.x, b.y, b.z, b.w};
#pragma unroll
      for (int i = 0; i < 4; ++i)
#pragma unroll
        for (int j = 0; j < 4; ++j) acc[i][j] = fmaf(da[i], db[j], acc[i][j]);
    }
    __syncthreads();
  }

  float s = 0.f;
#pragma unroll
  for (int i = 0; i < 4; ++i) {
    int row = row0 + ty * 4 + i;
    int col = col0 + tx * 4;
    float4 x = *reinterpret_cast<const float4*>(&roi[(size_t)row * INDIM + col]);
    float xs[4] = {x.x, x.y, x.z, x.w};
    float vals[4];
#pragma unroll
    for (int j = 0; j < 4; ++j) {
      float val = acc[i][j] + bias[col + j];
      float d = val - clip10(xs[j]);
      s += d * d;
      vals[j] = val;
    }
    *reinterpret_cast<float4*>(&Cout[(size_t)row * INDIM + col]) =
        make_float4(vals[0], vals[1], vals[2], vals[3]);
  }
  float t = block_sum256(s, sm);
  if (tid == 0) part[blockIdx.y * gridDim.x + blockIdx.x] = t;
}

// ---------------- embedding loss partial: sum((CB[id]-ze)^2) per row ---------
__global__ __launch_bounds__(256) void emb_partial(const int* __restrict__ ids,
                                                   const float* __restrict__ CB,
                                                   const float* __restrict__ ze,
                                                   float* __restrict__ part) {
  __shared__ float sm[4];
  int row = blockIdx.x;
  int id = ids[row];
  float4 q = *reinterpret_cast<const float4*>(&CB[(size_t)id * DIMV + threadIdx.x * 4]);
  float4 z = *reinterpret_cast<const float4*>(&ze[(size_t)row * DIMV + threadIdx.x * 4]);
  float dx = q.x - z.x, dy = q.y - z.y, dz = q.z - z.z, dw = q.w - z.w;
  float t = block_sum256(dx * dx + dy * dy + dz * dz + dw * dw, sm);
  if (threadIdx.x == 0) part[row] = t;
}

// ---------------- final reduce: 4 scalar losses ------------------------------
__global__ __launch_bounds__(256) void loss_final(const float* __restrict__ part1,
                                                  const float* __restrict__ part2,
                                                  float* __restrict__ scal) {
  __shared__ float sm[4];
  float s1 = 0.f;
  for (int i = threadIdx.x; i < 8192; i += 256) s1 += part1[i];
  float s2 = 0.f;
  for (int i = threadIdx.x; i < NROWS; i += 256) s2 += part2[i];
  float t1 = block_sum256(s1, sm);
  __syncthreads();
  float t2 = block_sum256(s2, sm);
  if (threadIdx.x == 0) {
    float recon_loss = t1 / 33554432.f;  // N * INDIM
    float emb = t2 / 16777216.f;         // N * DIM
    scal[0] = recon_loss + emb + 0.25f * emb;  // vq = recon + embed + 0.25*commit
    scal[1] = recon_loss;
    scal[2] = emb;
    scal[3] = emb;  // commitment forward value == embedding
  }
}

extern "C" void kernel_launch(void* const* d_in, const int* in_sizes, int n_in,
                              void* d_out, int out_size, void* d_ws, size_t ws_size,
                              hipStream_t stream) {
  const float* roi = (const float*)d_in[0];
  const float* Wp = (const float*)d_in[1];
  const float* bp = (const float*)d_in[2];
  const float* We = (const float*)d_in[3];
  const float* be = (const float*)d_in[4];
  const float* CB = (const float*)d_in[5];
  const float* Wd = (const float*)d_in[6];
  const float* bd = (const float*)d_in[7];
  const float* Wo = (const float*)d_in[8];
  const float* bo = (const float*)d_in[9];

  // float32 output layout: ids[N], z_q[N*DIM], recon[N*INDIM], 4 scalars, usage
  float* out = (float*)d_out;
  float* out_ids = out;
  float* out_zq = out + NROWS;
  float* out_recon = out_zq + (size_t)NROWS * DIMV;
  float* out_scal = out_recon + (size_t)NROWS * INDIM;
  float* out_usage = out_scal + 4;

  // workspace (~153 MB)
  float* ws = (float*)d_ws;
  float* z1 = ws;                                   // N*DIM (reused as h)
  float* ze = z1 + (size_t)NROWS * DIMV;            // N*DIM
  float* z2 = ze + (size_t)NROWS * DIMV;            // N
  float* c2 = z2 + NROWS;                           // NCODE
  float* pv = c2 + NCODE;                           // N*128
  int* pi = (int*)(pv + (size_t)NROWS * 128);       // N*128
  int* ids = pi + (size_t)NROWS * 128;              // N
  float* part1 = (float*)(ids + NROWS);             // 8192 (recon partials)
  float* part2 = part1 + 8192;                      // N (emb partials)

  zero_kernel<<<32, 256, 0, stream>>>(out_usage, NCODE);  // idempotent per call

  // z1 = clip(roi) @ Wp + bp ; z_e = z1 @ We + be  (np/OpenBLAS-faithful fp32)
  gemm_np<0, true><<<dim3(DIMV / 64, NROWS / 64), 256, 0, stream>>>(roi, Wp, bp, z1, NROWS,
                                                                    DIMV, INDIM);
  gemm_np<1, false><<<dim3(DIMV / 64, NROWS / 64), 256, 0, stream>>>(z1, We, be, ze, NROWS,
                                                                     DIMV, DIMV);
  // z2 = np.sum(z_e*z_e,1), c2 = np.sum(CB*CB,1)  (numpy pairwise emulation)
  rowsq_np<<<NROWS / 256, 256, 0, stream>>>(ze, NROWS, z2);
  rowsq_np<<<NCODE / 256, 256, 0, stream>>>(CB, NCODE, c2);

  // d = fl(fl(z2 - 2*(z_e@CB^T)) + c2); argmin with np first-index ties
  dist_np4<<<dim3(NCODE / 64, NROWS / 128), 256, 0, stream>>>(ze, CB, z2, c2, pv, pi);
  argmin_final<<<NROWS / 256, 256, 0, stream>>>(pv, pi, out_ids, ids, out_usage);
  gather_kernel<<<NROWS, 256, 0, stream>>>(ids, CB, out_zq);

  // decoder: h = CB[ids] @ Wd + bd ; recon = h @ Wo + bo (+ fused recon-loss)
  gemm_dec1<<<dim3(DIMV / 64, NROWS / 64), 256, 0, stream>>>(ids, CB, Wd, bd, z1);
  gemm_dec2<<<dim3(INDIM / 64, NROWS / 64), 256, 0, stream>>>(z1, Wo, bo, roi, out_recon,
                                                              part1);
  // embedding loss partials + final scalars
  emb_partial<<<NROWS, 256, 0, stream>>>(ids, CB, ze, part2);
  loss_final<<<1, 256, 0, stream>>>(part1, part2, out_scal);
}